// Round 4
// baseline (212.584 us; speedup 1.0000x reference)
//
#include <hip/hip_runtime.h>

// GRU fused, MI355X/gfx950 — round 4.
// vs r3 (which spilled: VGPR_Count=64, WRITE_SIZE 33MB): same 512-thr/8-wave
// shape (wave owns 16 cols/gate, MB=16) but ~30 fewer live regs so
// __launch_bounds__(512,4) holds WITHOUT spill:
//  - all 28 timesteps of x staged to LDS in prologue (no in-loop global
//    traffic, no prefetch registers, x read from HBM exactly once)
//  - double-buffered lh with ONE barrier per step (triple was overkill)
// Arch-reg audit: weights 48+12, bias 4, hm 4, addrs ~6, ha/xa 20 transient,
// temps ~8 => ~104 arch + 16 AGPR accs = ~120 <= 128 cap.

#define B_  16384
#define T_  28
#define F_  28
#define H_  128
#define C_  10
#define MB  16     // batch rows per block
#define LHS 136    // lh row stride in ushorts (272 B = 17*16: 16B-aligned rows)
#define LXS 32     // lx row stride in ushorts (64 B; k 0..27 data, 28..31 zero)

typedef short  short8  __attribute__((ext_vector_type(8)));
typedef float  f32x4   __attribute__((ext_vector_type(4)));

__device__ __forceinline__ unsigned short f2bf(float f) {   // RNE fp32->bf16
    unsigned u = __builtin_bit_cast(unsigned, f);
    u += 0x7fffu + ((u >> 16) & 1u);
    return (unsigned short)(u >> 16);
}
__device__ __forceinline__ float bf2f(unsigned short h) {
    unsigned u = ((unsigned)h) << 16;
    return __builtin_bit_cast(float, u);
}
__device__ __forceinline__ float fast_sig(float x) {
    float e = __builtin_amdgcn_exp2f(x * -1.442695040888963f);
    return __builtin_amdgcn_rcpf(1.0f + e);
}
__device__ __forceinline__ float fast_tanh(float x) {
    float e = __builtin_amdgcn_exp2f(x * 2.885390081777927f);
    return 1.0f - 2.0f * __builtin_amdgcn_rcpf(1.0f + e);
}

__global__ __launch_bounds__(512, 4)
void gru_fused(const float* __restrict__ x,     // (B,T,F)
               const float* __restrict__ wk,    // (F,3H)
               const float* __restrict__ wrk,   // (H,3H)
               const float* __restrict__ bias,  // (2,3H)
               const float* __restrict__ dw,    // (H,C)
               const float* __restrict__ db,    // (C,)
               float* __restrict__ out)         // (B,C)
{
    // ---- LDS (~38 KB) ----
    __shared__ __align__(16) unsigned short lh[2][MB*LHS];   // h bf16, double-buffered
    __shared__ __align__(16) unsigned short lx[T_*MB*LXS];   // ALL timesteps of x, bf16
    __shared__ float llog[MB][C_];

    const int tid  = threadIdx.x;
    const int base = blockIdx.x * MB;
    const int lane = tid & 63;
    const int wc   = tid >> 6;    // wave 0..7 -> 16-col slice per gate
    const int n    = lane & 15;   // MFMA: A row / D col
    const int q    = lane >> 4;   // MFMA quad
    const int u    = wc*16 + n;   // output column (0..127)

    // ---- loop-invariant weights -> registers ----
    // B-frag: elem(lane,j) = W[k = kb*32 + q*8 + j][u]
    short8 wz[4], wr[4], wh[4];   // W_r gates z/r/h: 48 VGPR
    short8 xz, xr, xh;            // input kernel (K 28 padded to 32): 12 VGPR
    #pragma unroll
    for (int kb = 0; kb < 4; ++kb) {
        const int k0 = kb*32 + q*8;
        short8 vz, vr, vh;
        #pragma unroll
        for (int j = 0; j < 8; ++j) {
            const float* wp = wrk + (size_t)(k0 + j)*384 + u;
            vz[j] = (short)f2bf(wp[0]);
            vr[j] = (short)f2bf(wp[128]);
            vh[j] = (short)f2bf(wp[256]);
        }
        wz[kb] = vz; wr[kb] = vr; wh[kb] = vh;
    }
    {
        short8 vz, vr, vh;
        #pragma unroll
        for (int j = 0; j < 8; ++j) {
            const int k = q*8 + j;
            if (k < F_) {
                const float* wp = wk + (size_t)k*384 + u;
                vz[j] = (short)f2bf(wp[0]);
                vr[j] = (short)f2bf(wp[128]);
                vh[j] = (short)f2bf(wp[256]);
            } else { vz[j] = 0; vr[j] = 0; vh[j] = 0; }
        }
        xz = vz; xr = vr; xh = vh;
    }
    // biases (bias_i row 0, bias_r row 384 of flat (2,3H))
    const float bz = bias[u]       + bias[384 + u];
    const float brr= bias[128 + u] + bias[512 + u];
    const float bx = bias[256 + u];
    const float bh = bias[640 + u];

    // ---- h0 = 0 (buffer 0) ----
    for (int i = tid; i < MB*LHS/2; i += 512) ((unsigned*)lh[0])[i] = 0u;

    // ---- stage ALL x for this block's 16 rows into LDS ----
    // thread i < 448 handles (row, t): 28 contiguous floats (112 B, 16B-aligned)
    if (tid < MB*T_) {
        const int row = tid / T_, t = tid - row*T_;
        const float* src = x + (size_t)(base + row)*(T_*F_) + t*F_;
        float4 f[7];
        #pragma unroll
        for (int s = 0; s < 7; ++s) f[s] = *(const float4*)(src + s*4);
        unsigned short* dst = &lx[(t*MB + row)*LXS];
        #pragma unroll
        for (int c = 0; c < 4; ++c) {
            short8 v;
            #pragma unroll
            for (int j = 0; j < 8; ++j) {
                const int k = c*8 + j;
                v[j] = (k < F_) ? (short)f2bf(((const float*)f)[k]) : (short)0;
            }
            *(short8*)(dst + c*8) = v;
        }
    }

    float hm[4];                  // fp32 h master, D-layout (row q*4+reg, col u)
    #pragma unroll
    for (int r = 0; r < 4; ++r) hm[r] = 0.f;

    // per-lane LDS addresses (ushort indices)
    const int haRd = n*LHS + q*8;            // + kb*32, in lh[br]
    const int hWr  = (q*4)*LHS + u;          // + reg*LHS, in lh[1-br]
    const int xRd  = n*LXS + q*8;            // + t*MB*LXS

    int br_ = 0;
    for (int t = 0; t < T_; ++t) {
        __syncthreads();   // step t-1 writes (h into br_) + prologue staging visible

        short8 ha[4], xa;
        #pragma unroll
        for (int kb = 0; kb < 4; ++kb)
            ha[kb] = *(const short8*)&lh[br_][haRd + kb*32];
        xa = *(const short8*)&lx[t*(MB*LXS) + xRd];

        f32x4 az = (f32x4){bz,bz,bz,bz};
        f32x4 ar = (f32x4){brr,brr,brr,brr};
        f32x4 ax = (f32x4){bx,bx,bx,bx};
        f32x4 ah = (f32x4){bh,bh,bh,bh};
        #pragma unroll
        for (int kb = 0; kb < 4; ++kb) {
            az = __builtin_amdgcn_mfma_f32_16x16x32_bf16(ha[kb], wz[kb], az, 0,0,0);
            ar = __builtin_amdgcn_mfma_f32_16x16x32_bf16(ha[kb], wr[kb], ar, 0,0,0);
            ah = __builtin_amdgcn_mfma_f32_16x16x32_bf16(ha[kb], wh[kb], ah, 0,0,0);
        }
        az = __builtin_amdgcn_mfma_f32_16x16x32_bf16(xa, xz, az, 0,0,0);
        ar = __builtin_amdgcn_mfma_f32_16x16x32_bf16(xa, xr, ar, 0,0,0);
        ax = __builtin_amdgcn_mfma_f32_16x16x32_bf16(xa, xh, ax, 0,0,0);

        // gates + h update; D layout: row = q*4+reg, col = u
        unsigned short* lw = &lh[br_ ^ 1][hWr];
        #pragma unroll
        for (int reg = 0; reg < 4; ++reg) {
            float z  = fast_sig(az[reg]);
            float r  = fast_sig(ar[reg]);
            float hh = fast_tanh(ax[reg] + r * ah[reg]);
            float hn = hh + z * (hm[reg] - hh);
            hm[reg]  = hn;
            lw[reg*LHS] = f2bf(hn);
        }
        br_ ^= 1;
    }

    // ---- dense + softmax epilogue (final h in lh[br_]) ----
    __syncthreads();
    if (tid < 64) {
        const int row = tid >> 2, qq = tid & 3;
        for (int c = qq; c < C_; c += 4) {
            float s = db[c];
            #pragma unroll
            for (int u0 = 0; u0 < H_; u0 += 8) {
                short8 hv = *(const short8*)&lh[br_][row*LHS + u0];
                #pragma unroll
                for (int j = 0; j < 8; ++j)
                    s += bf2f((unsigned short)hv[j]) * dw[(u0+j)*C_ + c];
            }
            llog[row][c] = s;
        }
    }
    __syncthreads();
    if (tid < MB) {
        const int row = tid;
        float m = llog[row][0];
        #pragma unroll
        for (int c = 1; c < C_; ++c) m = fmaxf(m, llog[row][c]);
        float e[C_], s = 0.f;
        #pragma unroll
        for (int c = 0; c < C_; ++c) {
            e[c] = __builtin_amdgcn_exp2f((llog[row][c] - m) * 1.442695040888963f);
            s += e[c];
        }
        const float inv = __builtin_amdgcn_rcpf(s);
        float* o = out + (size_t)(base + row)*C_;
        #pragma unroll
        for (int c = 0; c < C_; ++c) o[c] = e[c] * inv;
    }
}

extern "C" void kernel_launch(void* const* d_in, const int* in_sizes, int n_in,
                              void* d_out, int out_size, void* d_ws, size_t ws_size,
                              hipStream_t stream) {
    const float* x   = (const float*)d_in[0];
    const float* wk  = (const float*)d_in[1];
    const float* wrk = (const float*)d_in[2];
    const float* bs  = (const float*)d_in[3];
    const float* dw  = (const float*)d_in[4];
    const float* db  = (const float*)d_in[5];
    (void)in_sizes; (void)n_in; (void)out_size; (void)d_ws; (void)ws_size;
    gru_fused<<<dim3(B_/MB), dim3(512), 0, stream>>>(x, wk, wrk, bs, dw, db, (float*)d_out);
}

// Round 5
// 184.642 us; speedup vs baseline: 1.1513x; 1.1513x over previous
//
#include <hip/hip_runtime.h>

// GRU fused, MI355X/gfx950 — round 5.
// Base: r2 (97us, (256,2), MB=32, weights-in-regs, no spill). Changes:
//  - TRANSPOSED MFMA: mfma(W_frag, h_frag, acc) instead of (h, W): per-lane
//    frag data identical, D comes out [u][m] -> lane owns 4 consecutive
//    h-units per quad => h writeback is 4x ds_write_b64 (was 16x u16).
//  - Zero-C trick: first MFMA of each chain takes a loop-invariant zero f32x4
//    as C => no acc-init movs in the loop (was 64 movs/step).
//  - Bias folded into x pad row k=28 (=1.0) with kernel row 28 = bias combos;
//    recurrent h-bias handled by one add/cell.
//  - bf16 pack via v_perm (round-half-up), 2 values/inst.
//  - ALL 28 timesteps of x staged to LDS in the prologue (56KB; block total
//    ~76KB, 2 blocks/CU = 152KB <= 160KB). Zero in-loop global traffic.

#define B_  16384
#define T_  28
#define F_  28
#define H_  128
#define C_  10
#define MB  32     // batch rows per block
#define LHS 136    // lh row stride in ushorts (272 B, 16B-aligned rows)
#define LXS 32     // lx row stride in ushorts (64 B; k 0..27 data, 28=bias-1.0, 29..31=0)

typedef short  short8 __attribute__((ext_vector_type(8)));
typedef float  f32x4  __attribute__((ext_vector_type(4)));

__device__ __forceinline__ unsigned short f2bf(float f) {   // RNE fp32->bf16
    unsigned u = __builtin_bit_cast(unsigned, f);
    u += 0x7fffu + ((u >> 16) & 1u);
    return (unsigned short)(u >> 16);
}
__device__ __forceinline__ float bf2f(unsigned short h) {
    unsigned u = ((unsigned)h) << 16;
    return __builtin_bit_cast(float, u);
}
// pack two fp32 -> two bf16 in one dword (round-half-up + v_perm)
__device__ __forceinline__ unsigned pack_bf16(float lo, float hi) {
    unsigned a = __builtin_bit_cast(unsigned, lo) + 0x8000u;
    unsigned b = __builtin_bit_cast(unsigned, hi) + 0x8000u;
    return __builtin_amdgcn_perm(b, a, 0x07060302u);  // {a[31:16], b[31:16]}
}
__device__ __forceinline__ float fast_sig(float x) {
    float e = __builtin_amdgcn_exp2f(x * -1.442695040888963f);
    return __builtin_amdgcn_rcpf(1.0f + e);
}
__device__ __forceinline__ float fast_tanh(float x) {
    float e = __builtin_amdgcn_exp2f(x * 2.885390081777927f);
    return 1.0f - 2.0f * __builtin_amdgcn_rcpf(1.0f + e);
}

__global__ __launch_bounds__(256, 2)
void gru_fused(const float* __restrict__ x,     // (B,T,F)
               const float* __restrict__ wk,    // (F,3H)
               const float* __restrict__ wrk,   // (H,3H)
               const float* __restrict__ bias,  // (2,3H)
               const float* __restrict__ dw,    // (H,C)
               const float* __restrict__ db,    // (C,)
               float* __restrict__ out)         // (B,C)
{
    // ---- LDS (~76 KB) ----
    __shared__ __align__(16) unsigned short lh[2][MB*LHS];  // h bf16, double-buffered
    __shared__ __align__(16) unsigned short lx[T_][MB*LXS]; // all timesteps of x, bf16
    __shared__ float llog[MB][C_];

    const int tid  = threadIdx.x;
    const int base = blockIdx.x * MB;
    const int lane = tid & 63;
    const int wc   = tid >> 6;    // wave 0..3 -> 32-unit slice [wc*32, wc*32+32)
    const int n    = lane & 15;
    const int q    = lane >> 4;

    // ---- loop-invariant weights -> registers (A-operand frags) ----
    // frag elem(lane,j) = W[k = kb*32 + q*8 + j][unit u = wc*32 + ut*16 + n]
    short8 wz[2][4], wr[2][4], wh[2][4];   // W_r z/r/h: 96 VGPR
    short8 xz[2], xr[2], xh[2];            // kernel (K 28->32; row 28 = bias): 24 VGPR
    #pragma unroll
    for (int ut = 0; ut < 2; ++ut) {
        const int uw = wc*32 + ut*16 + n;
        #pragma unroll
        for (int kb = 0; kb < 4; ++kb) {
            const int k0 = kb*32 + q*8;
            short8 vz, vr, vh;
            #pragma unroll
            for (int j = 0; j < 8; ++j) {
                const float* wp = wrk + (size_t)(k0 + j)*384 + uw;
                vz[j] = (short)f2bf(wp[0]);
                vr[j] = (short)f2bf(wp[128]);
                vh[j] = (short)f2bf(wp[256]);
            }
            wz[ut][kb] = vz; wr[ut][kb] = vr; wh[ut][kb] = vh;
        }
        short8 vz, vr, vh;
        #pragma unroll
        for (int j = 0; j < 8; ++j) {
            const int k = q*8 + j;
            if (k < F_) {
                const float* wp = wk + (size_t)k*384 + uw;
                vz[j] = (short)f2bf(wp[0]);
                vr[j] = (short)f2bf(wp[128]);
                vh[j] = (short)f2bf(wp[256]);
            } else if (k == F_) {   // bias row (x[28] = 1.0)
                vz[j] = (short)f2bf(bias[uw]       + bias[384 + uw]);
                vr[j] = (short)f2bf(bias[128 + uw] + bias[512 + uw]);
                vh[j] = (short)f2bf(bias[256 + uw]);           // input-bias only
            } else { vz[j] = 0; vr[j] = 0; vh[j] = 0; }
        }
        xz[ut] = vz; xr[ut] = vr; xh[ut] = vh;
    }
    // recurrent h-gate bias for this lane's D cells (u = wc*32 + ut*16 + q*4 + reg)
    float brh[2][4];
    #pragma unroll
    for (int ut = 0; ut < 2; ++ut)
        #pragma unroll
        for (int reg = 0; reg < 4; ++reg)
            brh[ut][reg] = bias[640 + wc*32 + ut*16 + q*4 + reg];

    // ---- h0 = 0 ----
    for (int i = tid; i < MB*LHS/2; i += 256) ((unsigned*)lh[0])[i] = 0u;
    // ---- stage ALL x (28 t x 32 rows), pad k28=1.0 (bias), k29..31=0 ----
    for (int i = tid; i < MB*T_; i += 256) {
        const int t = i >> 5, row = i & 31;
        const float* src = x + (size_t)(base + row)*(T_*F_) + t*F_;
        float f[28];
        #pragma unroll
        for (int s = 0; s < 7; ++s) *(float4*)&f[s*4] = ((const float4*)src)[s];
        unsigned short* dst = &lx[t][row*LXS];
        #pragma unroll
        for (int c = 0; c < 4; ++c) {
            short8 v;
            #pragma unroll
            for (int j = 0; j < 8; ++j) {
                const int k = c*8 + j;
                v[j] = (k < F_) ? (short)f2bf(f[k])
                     : (k == F_ ? (short)0x3F80 : (short)0);
            }
            *(short8*)(dst + c*8) = v;
        }
    }

    const f32x4 zero4 = (f32x4){0.f, 0.f, 0.f, 0.f};
    float hm[2][2][4];            // fp32 h master [jt][ut][reg]; cell (m=jt*16+n, u=wc*32+ut*16+q*4+reg)
    #pragma unroll
    for (int jt = 0; jt < 2; ++jt)
        #pragma unroll
        for (int ut = 0; ut < 2; ++ut)
            #pragma unroll
            for (int r = 0; r < 4; ++r) hm[jt][ut][r] = 0.f;

    int cur = 0;
    for (int t = 0; t < T_; ++t) {
        __syncthreads();   // step t-1 h-writes (into cur) + prologue staging visible

        #pragma unroll
        for (int jt = 0; jt < 2; ++jt) {
            const int mrow = jt*16 + n;
            // B-frags: h^T and x^T for batch col mrow: B[k=q*8+j][m]
            short8 hb[4], xb;
            #pragma unroll
            for (int kb = 0; kb < 4; ++kb)
                hb[kb] = *(const short8*)&lh[cur][mrow*LHS + kb*32 + q*8];
            xb = *(const short8*)&lx[t][mrow*LXS + q*8];

            #pragma unroll
            for (int ut = 0; ut < 2; ++ut) {
                // x-side first (carries bias via k=28); C = persistent zero
                f32x4 az = __builtin_amdgcn_mfma_f32_16x16x32_bf16(xz[ut], xb, zero4, 0,0,0);
                f32x4 ar = __builtin_amdgcn_mfma_f32_16x16x32_bf16(xr[ut], xb, zero4, 0,0,0);
                f32x4 ax = __builtin_amdgcn_mfma_f32_16x16x32_bf16(xh[ut], xb, zero4, 0,0,0);
                f32x4 ah = __builtin_amdgcn_mfma_f32_16x16x32_bf16(wh[ut][0], hb[0], zero4, 0,0,0);
                #pragma unroll
                for (int kb = 0; kb < 4; ++kb) {
                    az = __builtin_amdgcn_mfma_f32_16x16x32_bf16(wz[ut][kb], hb[kb], az, 0,0,0);
                    ar = __builtin_amdgcn_mfma_f32_16x16x32_bf16(wr[ut][kb], hb[kb], ar, 0,0,0);
                    if (kb) ah = __builtin_amdgcn_mfma_f32_16x16x32_bf16(wh[ut][kb], hb[kb], ah, 0,0,0);
                }
                // gates; D layout (transposed): row q*4+reg = unit u, col n = batch m
                float hn[4];
                #pragma unroll
                for (int reg = 0; reg < 4; ++reg) {
                    float z  = fast_sig(az[reg]);
                    float r  = fast_sig(ar[reg]);
                    float hh = fast_tanh(ax[reg] + r * (ah[reg] + brh[ut][reg]));
                    float hv = hh + z * (hm[jt][ut][reg] - hh);
                    hm[jt][ut][reg] = hv;
                    hn[reg] = hv;
                }
                // pack 4 consecutive units -> one b64 LDS write
                uint2 p;
                p.x = pack_bf16(hn[0], hn[1]);
                p.y = pack_bf16(hn[2], hn[3]);
                *(uint2*)&lh[cur ^ 1][mrow*LHS + wc*32 + ut*16 + q*4] = p;
            }
        }
        cur ^= 1;
    }

    // ---- dense + softmax epilogue (final h in lh[cur]) ----
    __syncthreads();
    if (tid < 128) {
        const int row = tid >> 2, qq = tid & 3;
        for (int c = qq; c < C_; c += 4) {
            float s = db[c];
            #pragma unroll
            for (int u0 = 0; u0 < H_; u0 += 8) {
                short8 hv = *(const short8*)&lh[cur][row*LHS + u0];
                #pragma unroll
                for (int j = 0; j < 8; ++j)
                    s += bf2f((unsigned short)hv[j]) * dw[(u0+j)*C_ + c];
            }
            llog[row][c] = s;
        }
    }
    __syncthreads();
    if (tid < MB) {
        const int row = tid;
        float m = llog[row][0];
        #pragma unroll
        for (int c = 1; c < C_; ++c) m = fmaxf(m, llog[row][c]);
        float e[C_], s = 0.f;
        #pragma unroll
        for (int c = 0; c < C_; ++c) {
            e[c] = __builtin_amdgcn_exp2f((llog[row][c] - m) * 1.442695040888963f);
            s += e[c];
        }
        const float inv = __builtin_amdgcn_rcpf(s);
        float* o = out + (size_t)(base + row)*C_;
        #pragma unroll
        for (int c = 0; c < C_; ++c) o[c] = e[c] * inv;
    }
}

extern "C" void kernel_launch(void* const* d_in, const int* in_sizes, int n_in,
                              void* d_out, int out_size, void* d_ws, size_t ws_size,
                              hipStream_t stream) {
    const float* x   = (const float*)d_in[0];
    const float* wk  = (const float*)d_in[1];
    const float* wrk = (const float*)d_in[2];
    const float* bs  = (const float*)d_in[3];
    const float* dw  = (const float*)d_in[4];
    const float* db  = (const float*)d_in[5];
    (void)in_sizes; (void)n_in; (void)out_size; (void)d_ws; (void)ws_size;
    gru_fused<<<dim3(B_/MB), dim3(256), 0, stream>>>(x, wk, wrk, bs, dw, db, (float*)d_out);
}